// Round 7
// baseline (249.396 us; speedup 1.0000x reference)
//
#include <hip/hip_runtime.h>
#include <hip/hip_bf16.h>
#include <hip/hip_fp16.h>

#define NPOS 1296              // 36*36 oscillators
#define BATCH 512
#define STEPS 25
#define PH_STRIDE (BATCH * NPOS)            // 663552
#define PH_TOTAL ((STEPS + 1) * PH_STRIDE)  // 17252352
#define FC_K 3456
#define FC_N 864
#define FC_NPAD 1024           // pad to 8 col-tiles -> gemm grid 512 = 2.0 blocks/CU
#define FC_M 6144
#define KT_ITERS 54            // FC_K / 64

typedef float f32x4 __attribute__((ext_vector_type(4)));
typedef __bf16 bf16x8 __attribute__((ext_vector_type(8)));

__device__ __forceinline__ ushort f2bf(float f) {
  union { float f; unsigned u; } v; v.f = f;
  unsigned r = v.u + 0x7FFFu + ((v.u >> 16) & 1u);  // RNE
  return (ushort)(r >> 16);
}
__device__ __forceinline__ float bf2f(ushort h) {
  union { unsigned u; float f; } v; v.u = ((unsigned)h) << 16; return v.f;
}

__device__ __forceinline__ void async_copy16(void* lds, const void* g) {
  __builtin_amdgcn_global_load_lds(
      (const __attribute__((address_space(1))) unsigned*)g,
      (__attribute__((address_space(3))) unsigned*)lds, 16, 0, 0);
}
__device__ __forceinline__ void raw_barrier() { asm volatile("s_barrier" ::: "memory"); }
__device__ __forceinline__ void waitcnt_vm7() { asm volatile("s_waitcnt vmcnt(7)" ::: "memory"); }
__device__ __forceinline__ void waitcnt_vm0() { asm volatile("s_waitcnt vmcnt(0)" ::: "memory"); }

// ---------------- weight prep: transpose to MFMA-friendly [co][k] layouts ----------------
__global__ __launch_bounds__(256) void wprep_kernel(
    const float* __restrict__ w1, const float* __restrict__ w2, const float* __restrict__ w3,
    float* __restrict__ w1t, ushort* __restrict__ w2t, ushort* __restrict__ w3t) {
  const int tid = threadIdx.x;
  for (int i = tid; i < 72; i += 256) {
    const int s = i / 8, co = i - s * 8;
    w1t[i] = w1[co * 9 + s];
  }
  for (int i = tid; i < 16 * 96; i += 256) {
    const int co = i / 96, k = i - co * 96;
    const int s = k / 8, ci = k - s * 8;
    w2t[i] = (k < 72) ? f2bf(w2[(co * 8 + ci) * 9 + s]) : (ushort)0;
  }
  for (int i = tid; i < 32 * 160; i += 256) {
    const int co = i / 160, k = i - co * 160;
    const int s = k / 16, ci = k - s * 16;
    w3t[i] = (k < 144) ? f2bf(w3[(co * 16 + ci) * 9 + s]) : (ushort)0;
  }
}

// ---------------- fused conv1(VALU) + conv2(MFMA) + conv3(MFMA+sigmoid) ----------------
__global__ __launch_bounds__(256, 4) void conv_fused_kernel(
    const float* __restrict__ in, const float* __restrict__ w1t, const float* __restrict__ b1,
    const ushort* __restrict__ w2t, const float* __restrict__ b2,
    const ushort* __restrict__ w3t, const float* __restrict__ b3,
    ushort* __restrict__ aout) {
  __shared__ __align__(16) float sIn[18][40];          // input rows r0-3..r0+14, col x at x+2
  __shared__ __align__(16) ushort sC1[18][40][8];      // c1 rows r0-2..r0+13 (rows 16,17 zero)
  __shared__ __align__(16) ushort sC2[16][40][16];     // c2 rows r0-1..r0+12 (rows 14,15 zero)
  const int b = blockIdx.x, band = blockIdx.y, tid = threadIdx.x;
  const int r0 = band * 12;
  const int wave = tid >> 6, lane = tid & 63;
  const int quad = lane >> 4, l16 = lane & 15;
  {
    const uint4 zz = make_uint4(0, 0, 0, 0);
    for (int i = tid; i < 180; i += 256) ((uint4*)sIn)[i] = zz;
    for (int i = tid; i < 720; i += 256) ((uint4*)sC1)[i] = zz;
    for (int i = tid; i < 1280; i += 256) ((uint4*)sC2)[i] = zz;
  }
  __syncthreads();
  for (int i = tid; i < 18 * 18; i += 256) {
    const int r = i / 18, c = i - r * 18;
    const int gy = r0 - 3 + r;
    if ((unsigned)gy < 36u)
      *(float2*)&sIn[r][2 + 2 * c] = *(const float2*)(in + (size_t)b * NPOS + gy * 36 + 2 * c);
  }
  __syncthreads();
  // conv1
  for (int i = tid; i < 16 * 36; i += 256) {
    const int lr = i / 36, x = i - lr * 36;
    float acc[8];
#pragma unroll
    for (int co = 0; co < 8; ++co) acc[co] = b1[co];
#pragma unroll
    for (int s = 0; s < 9; ++s) {
      const int dy = s / 3, dx = s - 3 * dy;
      const float v = sIn[lr + dy][x + 1 + dx];
#pragma unroll
      for (int co = 0; co < 8; ++co) acc[co] = fmaf(w1t[s * 8 + co], v, acc[co]);
    }
    const int g1 = r0 - 2 + lr;
    if ((unsigned)g1 < 36u) {
      uint4 pk;
      pk.x = (uint)f2bf(fmaxf(acc[0], 0.f)) | ((uint)f2bf(fmaxf(acc[1], 0.f)) << 16);
      pk.y = (uint)f2bf(fmaxf(acc[2], 0.f)) | ((uint)f2bf(fmaxf(acc[3], 0.f)) << 16);
      pk.z = (uint)f2bf(fmaxf(acc[4], 0.f)) | ((uint)f2bf(fmaxf(acc[5], 0.f)) << 16);
      pk.w = (uint)f2bf(fmaxf(acc[6], 0.f)) | ((uint)f2bf(fmaxf(acc[7], 0.f)) << 16);
      *(uint4*)&sC1[lr][x + 2][0] = pk;
    }
  }
  __syncthreads();
  // conv2 via MFMA: M=512 px, N=16 co, K=96 (72 real)
  bf16x8 w2f[3];
#pragma unroll
  for (int f = 0; f < 3; ++f)
    w2f[f] = *(const bf16x8*)(w2t + l16 * 96 + f * 32 + quad * 8);
  const float bias2 = b2[l16];
  for (int chunk = wave; chunk < 32; chunk += 4) {
    const int m = chunk * 16 + l16;
    const int oy = m / 36, x = m - oy * 36;
    f32x4 acc = {0.f, 0.f, 0.f, 0.f};
#pragma unroll
    for (int f = 0; f < 3; ++f) {
      const int s0 = 4 * f + quad;
      const int dy = s0 / 3, dx = s0 - 3 * dy;
      const bf16x8 af = *(const bf16x8*)&sC1[oy + dy][x + 1 + dx][0];
      acc = __builtin_amdgcn_mfma_f32_16x16x32_bf16(af, w2f[f], acc, 0, 0, 0);
    }
#pragma unroll
    for (int r = 0; r < 4; ++r) {
      const int px = chunk * 16 + quad * 4 + r;
      const int oy2 = px / 36, x2 = px - oy2 * 36;
      const int g2 = r0 - 1 + oy2;
      if (px < 504 && (unsigned)g2 < 36u)
        sC2[oy2][x2 + 2][l16] = f2bf(fmaxf(acc[r] + bias2, 0.f));
    }
  }
  __syncthreads();
  // conv3 via MFMA: M=432 px, N=32 co (2 tiles), K=160 (144 real)
  bf16x8 w3f[2][5];
#pragma unroll
  for (int t = 0; t < 2; ++t)
#pragma unroll
    for (int f = 0; f < 5; ++f)
      w3f[t][f] = *(const bf16x8*)(w3t + (t * 16 + l16) * 160 + f * 32 + quad * 8);
  const float bias3a = b3[l16], bias3b = b3[16 + l16];
  ushort* ob = aout + (size_t)b * (32 * NPOS) + r0 * 36;
  for (int chunk = wave; chunk < 27; chunk += 4) {
    const int m = chunk * 16 + l16;
    const int oy = m / 36, x = m - oy * 36;
    f32x4 acc0 = {0.f, 0.f, 0.f, 0.f}, acc1 = {0.f, 0.f, 0.f, 0.f};
#pragma unroll
    for (int f = 0; f < 5; ++f) {
      const int s0 = 2 * f + (quad >> 1);
      const int dy = s0 / 3, dx = s0 - 3 * dy;
      const bf16x8 af = *(const bf16x8*)&sC2[oy + dy][x + 1 + dx][(quad & 1) * 8];
      acc0 = __builtin_amdgcn_mfma_f32_16x16x32_bf16(af, w3f[0][f], acc0, 0, 0, 0);
      acc1 = __builtin_amdgcn_mfma_f32_16x16x32_bf16(af, w3f[1][f], acc1, 0, 0, 0);
    }
    const int pxb = chunk * 16 + quad * 4;
    ushort4 pk;
#pragma unroll
    for (int r = 0; r < 4; ++r)
      ((ushort*)&pk)[r] = f2bf(1.f / (1.f + __expf(-(acc0[r] + bias3a))));
    *(ushort4*)(ob + (size_t)l16 * NPOS + pxb) = pk;
#pragma unroll
    for (int r = 0; r < 4; ++r)
      ((ushort*)&pk)[r] = f2bf(1.f / (1.f + __expf(-(acc1[r] + bias3b))));
    *(ushort4*)(ob + (size_t)(16 + l16) * NPOS + pxb) = pk;
  }
}

// ---------------- fc_w (864x3456 f32) -> bf16, rows padded to 1024 with zeros ----------------
__global__ __launch_bounds__(256) void wcvt_kernel(const float* __restrict__ w, ushort* __restrict__ wb) {
  const int idx = blockIdx.x * 256 + threadIdx.x;
  if (idx >= FC_NPAD * FC_K) return;
  const int n = idx / FC_K;
  wb[idx] = (n < FC_N) ? f2bf(w[idx]) : (ushort)0;
}

// ---------------- bf16 NT GEMM: C[m][n] = sum_k A[m][k]*Bt[n][k] + bias[n] ----------------
// 96x128 block tile, 4 waves of 48x64 (3x4 acc). Double-buffered LDS, raw s_barrier +
// s_waitcnt vmcnt(7) prefetch (tile kt+2 in flight during compute of kt+1). XOR-swizzled
// LDS cells. Grid 512 = exactly 2 blocks/CU (all co-resident, no tail), XCD-swizzled.
__global__ __launch_bounds__(256, 2) void gemm_kernel(
    const ushort* __restrict__ A, const ushort* __restrict__ Bt,
    const float* __restrict__ bias, float* __restrict__ C) {
  // buffer p: A slab s at [p][s*3072 + (r*4+o')*8], B slab s at [p][6144 + s*4096 + (r*4+o')*8]
  __shared__ __align__(16) ushort smem[2][14336];
  const int tid = threadIdx.x;
  const int lin = blockIdx.x;
  const int xcd = lin & 7, g = lin >> 3;           // 512 blocks: g 0..63
  const int bn = g & 7;                            // 8 col tiles (Npad=1024)
  const int bm = xcd + 8 * (g >> 3);               // 0..63
  const int row0 = bm * 96, col0 = bn * 128;
  const int wave = tid >> 6, lane = tid & 63;
  const int wr = (wave >> 1) * 48, wc = (wave & 1) * 64;
  const int quad = lane >> 4, l16 = lane & 15;
  const int oswz = (quad ^ ((l16 >> 1) & 3)) * 8;  // swizzled octet offset for fragment reads
  f32x4 acc[3][4] = {};

  // staging descriptors: 7 chunks/wave, chunk = 16 rows x 4 octets (64 lanes x 16B)
  const int rr = lane >> 2;                              // row within chunk
  const int soct = ((lane & 3) ^ ((lane >> 3) & 3)) * 8; // source k-octet (elems)
  const ushort* gsrc[7];
  const ushort* ldst[7];
  {
    const int s = wave >> 1;  // slab this wave-pair stages
    if ((wave & 1) == 0) {
      // 6 A-chunks + B-chunk 0 of slab s
#pragma unroll
      for (int j = 0; j < 6; ++j) {
        gsrc[j] = A + ((size_t)row0 + j * 16 + rr) * FC_K + s * 32 + soct;
        ldst[j] = &smem[0][s * 3072 + j * 512];
      }
      gsrc[6] = Bt + ((size_t)col0 + rr) * FC_K + s * 32 + soct;
      ldst[6] = &smem[0][6144 + s * 4096];
    } else {
      // B-chunks 1..7 of slab s
#pragma unroll
      for (int j = 0; j < 7; ++j) {
        gsrc[j] = Bt + ((size_t)col0 + (j + 1) * 16 + rr) * FC_K + s * 32 + soct;
        ldst[j] = &smem[0][6144 + s * 4096 + (j + 1) * 512];
      }
    }
  }
  // prologue: tiles 0 and 1 in flight
#pragma unroll
  for (int j = 0; j < 7; ++j) async_copy16((void*)ldst[j], gsrc[j]);
#pragma unroll
  for (int j = 0; j < 7; ++j) async_copy16((void*)(ldst[j] + 14336), gsrc[j] + 64);

  for (int kt = 0; kt < KT_ITERS; ++kt) {
    const int p = kt & 1;
    waitcnt_vm7();          // oldest 7 (this tile's chunks) complete; prefetch stays in flight
    raw_barrier();
    const ushort* base = &smem[p][0];
#pragma unroll
    for (int s = 0; s < 2; ++s) {
      bf16x8 af[3], bfr[4];
#pragma unroll
      for (int t = 0; t < 3; ++t)
        af[t] = *(const bf16x8*)(base + s * 3072 + (wr + t * 16 + l16) * 32 + oswz);
#pragma unroll
      for (int t = 0; t < 4; ++t)
        bfr[t] = *(const bf16x8*)(base + 6144 + s * 4096 + (wc + t * 16 + l16) * 32 + oswz);
#pragma unroll
      for (int tm = 0; tm < 3; ++tm)
#pragma unroll
        for (int tn = 0; tn < 4; ++tn)
          acc[tm][tn] = __builtin_amdgcn_mfma_f32_16x16x32_bf16(af[tm], bfr[tn], acc[tm][tn], 0, 0, 0);
    }
    raw_barrier();          // everyone done reading buffer p
    int kn = kt + 2;
    if (kn >= KT_ITERS) kn -= KT_ITERS;   // wrap: harmless extra tile keeps vmcnt uniform
    const int koff = kn * 64;
#pragma unroll
    for (int j = 0; j < 7; ++j) async_copy16((void*)(ldst[j] + p * 14336), gsrc[j] + koff);
  }
  waitcnt_vm0();            // drain dangling wrap copies before workgroup end

#pragma unroll
  for (int tn = 0; tn < 4; ++tn) {
    const int col = col0 + wc + tn * 16 + l16;
    if (col < FC_N) {
      const float bv = bias[col];
#pragma unroll
      for (int tm = 0; tm < 3; ++tm) {
#pragma unroll
        for (int r = 0; r < 4; ++r) {
          const int row = row0 + wr + tm * 16 + quad * 4 + r;
          C[(size_t)row * FC_N + col] = acc[tm][tn][r] + bv;
        }
      }
    }
  }
}

// ---------------- Kuramoto: one block (512 threads) per batch, 25 steps ----------------
// Phases + own sin/cos in f32 registers; neighbor sin/cos in LDS as __half2 (4B -> single-bank
// random gathers); double-buffered -> ONE barrier per step.
__global__ __launch_bounds__(512) void kuramoto_kernel(
    const float* __restrict__ ph0, const int* __restrict__ conn,
    const float* __restrict__ cpl, float* __restrict__ out) {
  __shared__ __half2 sc[2][NPOS];
  const int b = blockIdx.x, tid = threadIdx.x;
  int rj[3][8];
  float rc[3][8];
  float myph[3];
  float2 mysc[3];
#pragma unroll
  for (int s = 0; s < 3; ++s) {
    const int i = tid + s * 512;
    if (i < NPOS) {
      const float p = ph0[(size_t)b * NPOS + i];
      myph[s] = p;
      __builtin_nontemporal_store(p, out + (size_t)b * NPOS + i);  // step 0
      float sn, cn;
      __sincosf(p, &sn, &cn);
      mysc[s] = make_float2(sn, cn);
      sc[0][i] = __floats2half2_rn(sn, cn);
      const size_t base = (size_t)b * (NPOS * 8) + (size_t)i * 8;
      const int4 j0 = *(const int4*)(conn + base);
      const int4 j1 = *(const int4*)(conn + base + 4);
      const float4 c0 = *(const float4*)(cpl + base);
      const float4 c1 = *(const float4*)(cpl + base + 4);
      rj[s][0] = j0.x; rj[s][1] = j0.y; rj[s][2] = j0.z; rj[s][3] = j0.w;
      rj[s][4] = j1.x; rj[s][5] = j1.y; rj[s][6] = j1.z; rj[s][7] = j1.w;
      rc[s][0] = c0.x; rc[s][1] = c0.y; rc[s][2] = c0.z; rc[s][3] = c0.w;
      rc[s][4] = c1.x; rc[s][5] = c1.y; rc[s][6] = c1.z; rc[s][7] = c1.w;
    }
  }
  float ep = 0.1f;
  for (int t = 0; t < STEPS; ++t) {
    __syncthreads();          // step t-1's sc writes visible
    const int cur = t & 1;
    float* op = out + (size_t)(t + 1) * PH_STRIDE + (size_t)b * NPOS;
#pragma unroll
    for (int s = 0; s < 3; ++s) {
      const int i = tid + s * 512;
      if (i < NPOS) {
        float ss = 0.f, cc = 0.f;
#pragma unroll
        for (int k = 0; k < 8; ++k) {
          const float2 v = __half22float2(sc[cur][rj[s][k]]);
          ss = fmaf(rc[s][k], v.x, ss);
          cc = fmaf(rc[s][k], v.y, cc);
        }
        const float np = myph[s] + ep * (mysc[s].y * ss - mysc[s].x * cc);
        myph[s] = np;
        __builtin_nontemporal_store(np, op + i);
        float sn, cn;
        __sincosf(np, &sn, &cn);
        mysc[s] = make_float2(sn, cn);
        sc[cur ^ 1][i] = __floats2half2_rn(sn, cn);   // other buffer: no race
      }
    }
    ep = ep * (1.0f - 0.02f * (float)t);  // ep -= 0.5*t*ep/25
  }
}

extern "C" void kernel_launch(void* const* d_in, const int* in_sizes, int n_in,
                              void* d_out, int out_size, void* d_ws, size_t ws_size,
                              hipStream_t stream) {
  const float* input = (const float*)d_in[0];
  const float* ph0   = (const float*)d_in[1];
  const int*   conn  = (const int*)d_in[2];
  // d_in[3] = episodes (always 25)
  const float* w1 = (const float*)d_in[4];
  const float* b1 = (const float*)d_in[5];
  const float* w2 = (const float*)d_in[6];
  const float* b2 = (const float*)d_in[7];
  const float* w3 = (const float*)d_in[8];
  const float* b3 = (const float*)d_in[9];
  const float* fcw = (const float*)d_in[10];
  const float* fcb = (const float*)d_in[11];
  float* out = (float*)d_out;

  // workspace layout (bytes):
  // Abuf bf16 [0, 42467328) | Wbuf bf16 1024x3456 [42467328, 49545216) | w1t f32 (+288)
  // w2t bf16 (+3072) | w3t bf16 (+10240)
  ushort* Abuf = (ushort*)d_ws;
  ushort* Wbuf = (ushort*)((char*)d_ws + 42467328);
  float*  w1t  = (float*)((char*)d_ws + 49545216);
  ushort* w2t  = (ushort*)((char*)d_ws + 49545504);
  ushort* w3t  = (ushort*)((char*)d_ws + 49548576);
  float* fcout = out + PH_TOTAL;

  wprep_kernel<<<1, 256, 0, stream>>>(w1, w2, w3, w1t, w2t, w3t);
  wcvt_kernel<<<(FC_NPAD * FC_K) / 256, 256, 0, stream>>>(fcw, Wbuf);
  conv_fused_kernel<<<dim3(BATCH, 3), 256, 0, stream>>>(input, w1t, b1, w2t, b2, w3t, b3, Abuf);
  gemm_kernel<<<512, 256, 0, stream>>>(Abuf, Wbuf, fcb, fcout);
  kuramoto_kernel<<<BATCH, 512, 0, stream>>>(ph0, conn, fcout, out);
}